// Round 1
// baseline (947.821 us; speedup 1.0000x reference)
//
#include <hip/hip_runtime.h>
#include <hip/hip_bf16.h>

// HET relational attention layer, fp32 baseline.
// Pipeline:
//  K0 build_wext : W_ext[128][576] = [proj cols (512) | el cols (32) | er cols (32)]
//  K1 gemm_proj  : proj(bf16)[N,512] and elr(f32)[N,64] = inputs[N,128] @ W_ext
//  K2 init_out   : out = bias broadcast, denom = 0
//  K3 edge_denom : denom[dst,h] += exp(leaky(el[src,r,h]+er[dst,r,h]))   (no max-shift; scores are O(10))
//  K4 edge_agg   : out[dst,c]   += (exp(score)/denom) * proj[src,r,c]    (1 wave per edge, 64 lanes)

#define NN 100000
#define NE 1600000
#define NRL 8
#define NH 4
#define INF_ 128
#define OUTF 64
#define DH 16
#define NCOL 576
#define LEAKY 0.2f

typedef __hip_bfloat16 bf16;

__global__ void build_wext(const float* __restrict__ W, const float* __restrict__ al,
                           const float* __restrict__ ar, float* __restrict__ wext) {
    int idx = blockIdx.x * 256 + threadIdx.x;
    if (idx >= INF_ * NCOL) return;
    int i = idx / NCOL, c = idx % NCOL;
    float v;
    if (c < 512) {
        int r = c >> 6, rem = c & 63, h = rem >> 4, d = rem & 15;
        v = W[((r * NH + h) * INF_ + i) * DH + d];
    } else {
        int rh = c - 512;
        const float* a = al;
        if (rh >= 32) { rh -= 32; a = ar; }
        int r = rh >> 2, h = rh & 3;
        const float* wp = &W[((r * NH + h) * INF_ + i) * DH];
        const float* ap = &a[(r * NH + h) * DH];
        float s = 0.f;
        #pragma unroll
        for (int d = 0; d < DH; ++d) s += wp[d] * ap[d];
        v = s;
    }
    wext[i * NCOL + c] = v;
}

// 64x64 tile, K=128 in one shot, 256 threads, 4x4 per thread.
__global__ __launch_bounds__(256) void gemm_proj(
    const float* __restrict__ A, const float* __restrict__ Wx,
    bf16* __restrict__ projb, float* __restrict__ elr) {
    __shared__ float As[64][132];   // +4 pad: A-reads 2-way banked (free), float4-aligned
    __shared__ float Bs[128][64];
    int n0 = blockIdx.x * 64, c0 = blockIdx.y * 64;
    int t = threadIdx.x;

    #pragma unroll
    for (int it = 0; it < 8; ++it) {           // A: 64x128 = 2048 float4
        int f4 = it * 256 + t;
        int r = f4 >> 5, c4 = f4 & 31;
        int gr = n0 + r;
        float4 v = (gr < NN) ? *(const float4*)&A[gr * INF_ + c4 * 4]
                             : make_float4(0.f, 0.f, 0.f, 0.f);
        *(float4*)&As[r][c4 * 4] = v;
    }
    #pragma unroll
    for (int it = 0; it < 8; ++it) {           // B: 128x64 = 2048 float4
        int f4 = it * 256 + t;
        int k = f4 >> 4, j4 = f4 & 15;
        *(float4*)&Bs[k][j4 * 4] = *(const float4*)&Wx[k * NCOL + c0 + j4 * 4];
    }
    __syncthreads();

    int tx = t & 15, ty = t >> 4;
    float acc[4][4] = {};
    for (int k0 = 0; k0 < 128; k0 += 4) {
        float bb[4][4];
        #pragma unroll
        for (int kk = 0; kk < 4; ++kk) {
            float4 b = *(const float4*)&Bs[k0 + kk][tx * 4];
            bb[kk][0] = b.x; bb[kk][1] = b.y; bb[kk][2] = b.z; bb[kk][3] = b.w;
        }
        #pragma unroll
        for (int i = 0; i < 4; ++i) {
            float4 a = *(const float4*)&As[ty * 4 + i][k0];
            #pragma unroll
            for (int j = 0; j < 4; ++j)
                acc[i][j] += a.x * bb[0][j] + a.y * bb[1][j] + a.z * bb[2][j] + a.w * bb[3][j];
        }
    }

    #pragma unroll
    for (int i = 0; i < 4; ++i) {
        int n = n0 + ty * 4 + i;
        if (n >= NN) continue;
        #pragma unroll
        for (int j = 0; j < 4; ++j) {
            int c = c0 + tx * 4 + j;
            float v = acc[i][j];
            if (c < 512) projb[n * 512 + c] = __float2bfloat16(v);
            else         elr[n * 64 + (c - 512)] = v;
        }
    }
}

__global__ void init_out(float* __restrict__ out, const float* __restrict__ bias,
                         float* __restrict__ denom) {
    int tid = blockIdx.x * 256 + threadIdx.x;
    if (tid < NN * OUTF) out[tid] = bias[tid & 63];
    if (tid < NN * NH) denom[tid] = 0.f;
}

__global__ void edge_denom(const int* __restrict__ src, const int* __restrict__ dst,
                           const int* __restrict__ rel, const float* __restrict__ elr,
                           float* __restrict__ denom) {
    int e = blockIdx.x * 256 + threadIdx.x;
    if (e >= NE) return;
    int s = src[e], d = dst[e], r = rel[e];
    float4 el4 = *(const float4*)&elr[s * 64 + r * 4];
    float4 er4 = *(const float4*)&elr[d * 64 + 32 + r * 4];
    float sc[4] = {el4.x + er4.x, el4.y + er4.y, el4.z + er4.z, el4.w + er4.w};
    #pragma unroll
    for (int h = 0; h < 4; ++h) {
        float x = sc[h];
        x = x > 0.f ? x : LEAKY * x;
        atomicAdd(&denom[d * 4 + h], expf(x));
    }
}

__global__ __launch_bounds__(256) void edge_agg(
    const int* __restrict__ src, const int* __restrict__ dst, const int* __restrict__ rel,
    const float* __restrict__ elr, const float* __restrict__ denom,
    const bf16* __restrict__ projb, float* __restrict__ out) {
    int tid = blockIdx.x * 256 + threadIdx.x;   // max 102.4M < 2^31
    int e = tid >> 6;
    if (e >= NE) return;
    int c = tid & 63;
    int s = src[e], d = dst[e], r = rel[e];
    int h = c >> 4;
    float el = elr[s * 64 + r * 4 + h];
    float er = elr[d * 64 + 32 + r * 4 + h];
    float x = el + er;
    x = x > 0.f ? x : LEAKY * x;
    float alpha = expf(x) / denom[d * 4 + h];
    float v = __bfloat162float(projb[(s * 8 + r) * 64 + c]);
    atomicAdd(&out[d * 64 + c], alpha * v);
}

extern "C" void kernel_launch(void* const* d_in, const int* in_sizes, int n_in,
                              void* d_out, int out_size, void* d_ws, size_t ws_size,
                              hipStream_t stream) {
    const float* inputs = (const float*)d_in[0];
    const float* convw  = (const float*)d_in[1];
    const float* attn_l = (const float*)d_in[2];
    const float* attn_r = (const float*)d_in[3];
    const float* h_bias = (const float*)d_in[4];
    const int*   src    = (const int*)d_in[5];
    const int*   dst    = (const int*)d_in[6];
    const int*   rel    = (const int*)d_in[7];
    float* out = (float*)d_out;

    char* ws = (char*)d_ws;
    float* wext  = (float*)ws;                                    //     294,912 B
    bf16*  projb = (bf16*)(ws + 294912);                          // 102,400,000 B
    float* elr   = (float*)(ws + 294912 + 102400000);             //  25,600,000 B
    float* denom = (float*)(ws + 294912 + 102400000 + 25600000);  //   1,600,000 B

    hipLaunchKernelGGL(build_wext, dim3(288), dim3(256), 0, stream, convw, attn_l, attn_r, wext);
    hipLaunchKernelGGL(gemm_proj, dim3(1563, 9), dim3(256), 0, stream, inputs, wext, projb, elr);
    hipLaunchKernelGGL(init_out, dim3(25000), dim3(256), 0, stream, out, h_bias, denom);
    hipLaunchKernelGGL(edge_denom, dim3(6250), dim3(256), 0, stream, src, dst, rel, elr, denom);
    hipLaunchKernelGGL(edge_agg, dim3(400000), dim3(256), 0, stream, src, dst, rel, elr, denom, projb, out);
}

// Round 2
// 621.167 us; speedup vs baseline: 1.5259x; 1.5259x over previous
//
#include <hip/hip_runtime.h>
#include <hip/hip_bf16.h>

// HET relational attention layer.
// Pipeline:
//  K0 build_wext : W_ext[128][576] = [proj cols (512) | el cols (32) | er cols (32)]
//  K1 gemm_proj  : proj(bf16)[N,512] and elr(f32)[N,64] = inputs[N,128] @ W_ext
//  CSR build     : zero -> count (atomic) -> 2-level scan -> scatter (src*8+rel per slot)
//  K_agg         : 1 wave per dst node; pass1 lane-parallel denom + shfl reduce,
//                  pass2 lane=column serial accumulate; single coalesced store.
// No segment-max shift: scores ~N(0,2), exp() safe in fp32 (softmax shift-invariant).

#define NN 100000
#define NE 1600000
#define NRL 8
#define NH 4
#define INF_ 128
#define OUTF 64
#define DH 16
#define NCOL 576
#define LEAKY 0.2f
#define NBLK_SCAN 98   // ceil(100000/1024)

typedef __hip_bfloat16 bf16;

__global__ void build_wext(const float* __restrict__ W, const float* __restrict__ al,
                           const float* __restrict__ ar, float* __restrict__ wext) {
    int idx = blockIdx.x * 256 + threadIdx.x;
    if (idx >= INF_ * NCOL) return;
    int i = idx / NCOL, c = idx % NCOL;
    float v;
    if (c < 512) {
        int r = c >> 6, rem = c & 63, h = rem >> 4, d = rem & 15;
        v = W[((r * NH + h) * INF_ + i) * DH + d];
    } else {
        int rh = c - 512;
        const float* a = al;
        if (rh >= 32) { rh -= 32; a = ar; }
        int r = rh >> 2, h = rh & 3;
        const float* wp = &W[((r * NH + h) * INF_ + i) * DH];
        const float* ap = &a[(r * NH + h) * DH];
        float s = 0.f;
        #pragma unroll
        for (int d = 0; d < DH; ++d) s += wp[d] * ap[d];
        v = s;
    }
    wext[i * NCOL + c] = v;
}

// 64x64 tile, K=128 in one shot, 256 threads, 4x4 per thread. fp32 (MFMA next round).
__global__ __launch_bounds__(256) void gemm_proj(
    const float* __restrict__ A, const float* __restrict__ Wx,
    bf16* __restrict__ projb, float* __restrict__ elr) {
    __shared__ float As[64][132];
    __shared__ float Bs[128][64];
    int n0 = blockIdx.x * 64, c0 = blockIdx.y * 64;
    int t = threadIdx.x;

    #pragma unroll
    for (int it = 0; it < 8; ++it) {
        int f4 = it * 256 + t;
        int r = f4 >> 5, c4 = f4 & 31;
        int gr = n0 + r;
        float4 v = (gr < NN) ? *(const float4*)&A[gr * INF_ + c4 * 4]
                             : make_float4(0.f, 0.f, 0.f, 0.f);
        *(float4*)&As[r][c4 * 4] = v;
    }
    #pragma unroll
    for (int it = 0; it < 8; ++it) {
        int f4 = it * 256 + t;
        int k = f4 >> 4, j4 = f4 & 15;
        *(float4*)&Bs[k][j4 * 4] = *(const float4*)&Wx[k * NCOL + c0 + j4 * 4];
    }
    __syncthreads();

    int tx = t & 15, ty = t >> 4;
    float acc[4][4] = {};
    for (int k0 = 0; k0 < 128; k0 += 4) {
        float bb[4][4];
        #pragma unroll
        for (int kk = 0; kk < 4; ++kk) {
            float4 b = *(const float4*)&Bs[k0 + kk][tx * 4];
            bb[kk][0] = b.x; bb[kk][1] = b.y; bb[kk][2] = b.z; bb[kk][3] = b.w;
        }
        #pragma unroll
        for (int i = 0; i < 4; ++i) {
            float4 a = *(const float4*)&As[ty * 4 + i][k0];
            #pragma unroll
            for (int j = 0; j < 4; ++j)
                acc[i][j] += a.x * bb[0][j] + a.y * bb[1][j] + a.z * bb[2][j] + a.w * bb[3][j];
        }
    }

    #pragma unroll
    for (int i = 0; i < 4; ++i) {
        int n = n0 + ty * 4 + i;
        if (n >= NN) continue;
        #pragma unroll
        for (int j = 0; j < 4; ++j) {
            int c = c0 + tx * 4 + j;
            float v = acc[i][j];
            if (c < 512) projb[n * 512 + c] = __float2bfloat16(v);
            else         elr[n * 64 + (c - 512)] = v;
        }
    }
}

__global__ void zero_counts(int* __restrict__ counts) {
    int i = blockIdx.x * 256 + threadIdx.x;
    if (i < NN) counts[i] = 0;
}

__global__ void count_edges(const int* __restrict__ dst, int* __restrict__ counts) {
    int e = blockIdx.x * 256 + threadIdx.x;
    if (e < NE) atomicAdd(&counts[dst[e]], 1);
}

// 1024 elements per block of 256 threads; exclusive scan within block.
__global__ __launch_bounds__(256) void scan_block(const int* __restrict__ counts,
                                                  int* __restrict__ offsets,
                                                  int* __restrict__ blockSums) {
    __shared__ int tsum[256];
    int b = blockIdx.x, t = threadIdx.x;
    int base = b * 1024 + t * 4;
    int v0 = (base + 0 < NN) ? counts[base + 0] : 0;
    int v1 = (base + 1 < NN) ? counts[base + 1] : 0;
    int v2 = (base + 2 < NN) ? counts[base + 2] : 0;
    int v3 = (base + 3 < NN) ? counts[base + 3] : 0;
    int own = v0 + v1 + v2 + v3;
    tsum[t] = own;
    __syncthreads();
    for (int st = 1; st < 256; st <<= 1) {
        int y = (t >= st) ? tsum[t - st] : 0;
        __syncthreads();
        tsum[t] += y;
        __syncthreads();
    }
    int excl = tsum[t] - own;   // sum of thread sums 0..t-1
    if (base + 0 < NN) offsets[base + 0] = excl;
    if (base + 1 < NN) offsets[base + 1] = excl + v0;
    if (base + 2 < NN) offsets[base + 2] = excl + v0 + v1;
    if (base + 3 < NN) offsets[base + 3] = excl + v0 + v1 + v2;
    if (t == 255) blockSums[b] = tsum[255];
}

__global__ __launch_bounds__(128) void scan_top(const int* __restrict__ blockSums,
                                                int* __restrict__ blockOff) {
    __shared__ int sb[128];
    int t = threadIdx.x;
    int own = (t < NBLK_SCAN) ? blockSums[t] : 0;
    sb[t] = own;
    __syncthreads();
    for (int st = 1; st < 128; st <<= 1) {
        int y = (t >= st) ? sb[t - st] : 0;
        __syncthreads();
        sb[t] += y;
        __syncthreads();
    }
    blockOff[t] = sb[t] - own;
}

__global__ void scan_add(int* __restrict__ offsets, const int* __restrict__ blockOff,
                         int* __restrict__ cursor) {
    int i = blockIdx.x * 256 + threadIdx.x;
    if (i < NN) {
        int v = offsets[i] + blockOff[i >> 10];
        offsets[i] = v;
        cursor[i] = v;
    }
    if (i == 0) offsets[NN] = NE;
}

__global__ void scatter_edges(const int* __restrict__ src, const int* __restrict__ dst,
                              const int* __restrict__ rel, int* __restrict__ cursor,
                              int* __restrict__ rec_srcrel) {
    int e = blockIdx.x * 256 + threadIdx.x;
    if (e >= NE) return;
    int d = dst[e];
    int pos = atomicAdd(&cursor[d], 1);
    rec_srcrel[pos] = src[e] * 8 + rel[e];
}

// One wave per dst node. 4 waves / 256-thread block.
__global__ __launch_bounds__(256) void agg(
    const int* __restrict__ offsets, const int* __restrict__ rec_srcrel,
    const float* __restrict__ elr, const bf16* __restrict__ projb,
    const float* __restrict__ bias, float* __restrict__ out) {
    int d = blockIdx.x * 4 + (threadIdx.x >> 6);
    if (d >= NN) return;
    int lane = threadIdx.x & 63;
    int off = offsets[d], end = offsets[d + 1];

    // pass 1: softmax denominator per head (lane-parallel over edges)
    float dsum0 = 0.f, dsum1 = 0.f, dsum2 = 0.f, dsum3 = 0.f;
    for (int i = off + lane; i < end; i += 64) {
        int sr = rec_srcrel[i];
        int s = sr >> 3, r = sr & 7;
        float4 el4 = *(const float4*)&elr[s * 64 + r * 4];
        float4 er4 = *(const float4*)&elr[d * 64 + 32 + r * 4];
        float x;
        x = el4.x + er4.x; x = x > 0.f ? x : LEAKY * x; dsum0 += __expf(x);
        x = el4.y + er4.y; x = x > 0.f ? x : LEAKY * x; dsum1 += __expf(x);
        x = el4.z + er4.z; x = x > 0.f ? x : LEAKY * x; dsum2 += __expf(x);
        x = el4.w + er4.w; x = x > 0.f ? x : LEAKY * x; dsum3 += __expf(x);
    }
    #pragma unroll
    for (int m = 32; m; m >>= 1) {
        dsum0 += __shfl_xor(dsum0, m, 64);
        dsum1 += __shfl_xor(dsum1, m, 64);
        dsum2 += __shfl_xor(dsum2, m, 64);
        dsum3 += __shfl_xor(dsum3, m, 64);
    }

    // pass 2: lane owns output column c; serial over edges
    int c = lane, h = c >> 4;
    float dh = (h == 0) ? dsum0 : (h == 1) ? dsum1 : (h == 2) ? dsum2 : dsum3;
    float rd = 1.0f / dh;                 // unused (loop empty) when end==off
    float acc = 0.f;
    for (int i = off; i < end; ++i) {
        int sr = rec_srcrel[i];           // uniform across wave -> broadcast
        int s = sr >> 3, r = sr & 7;
        float el = elr[s * 64 + r * 4 + h];
        float er = elr[d * 64 + 32 + r * 4 + h];
        float x = el + er;
        x = x > 0.f ? x : LEAKY * x;
        float alpha = __expf(x) * rd;
        acc += alpha * __bfloat162float(projb[sr * 64 + c]);
    }
    out[d * 64 + c] = acc + bias[c];
}

extern "C" void kernel_launch(void* const* d_in, const int* in_sizes, int n_in,
                              void* d_out, int out_size, void* d_ws, size_t ws_size,
                              hipStream_t stream) {
    const float* inputs = (const float*)d_in[0];
    const float* convw  = (const float*)d_in[1];
    const float* attn_l = (const float*)d_in[2];
    const float* attn_r = (const float*)d_in[3];
    const float* h_bias = (const float*)d_in[4];
    const int*   src    = (const int*)d_in[5];
    const int*   dst    = (const int*)d_in[6];
    const int*   rel    = (const int*)d_in[7];
    float* out = (float*)d_out;

    char* ws = (char*)d_ws;
    size_t o = 0;
    float* wext  = (float*)(ws + o); o += 294912;
    bf16*  projb = (bf16*)(ws + o);  o += 102400000ull;
    float* elr   = (float*)(ws + o); o += 25600000ull;
    int* offsets = (int*)(ws + o);   o += 400128;        // NN+1 ints, padded
    int* cursor  = (int*)(ws + o);   o += 400000;        // counts, then scatter cursors
    int* blockSums = (int*)(ws + o); o += 512;
    int* blockOff  = (int*)(ws + o); o += 512;
    int* rec_srcrel = (int*)(ws + o); o += 6400000ull;

    hipLaunchKernelGGL(build_wext, dim3(288), dim3(256), 0, stream, convw, attn_l, attn_r, wext);
    hipLaunchKernelGGL(gemm_proj, dim3(1563, 9), dim3(256), 0, stream, inputs, wext, projb, elr);
    hipLaunchKernelGGL(zero_counts, dim3(391), dim3(256), 0, stream, cursor);
    hipLaunchKernelGGL(count_edges, dim3(6250), dim3(256), 0, stream, dst, cursor);
    hipLaunchKernelGGL(scan_block, dim3(NBLK_SCAN), dim3(256), 0, stream, cursor, offsets, blockSums);
    hipLaunchKernelGGL(scan_top, dim3(1), dim3(128), 0, stream, blockSums, blockOff);
    hipLaunchKernelGGL(scan_add, dim3(391), dim3(256), 0, stream, offsets, blockOff, cursor);
    hipLaunchKernelGGL(scatter_edges, dim3(6250), dim3(256), 0, stream, src, dst, rel, cursor, rec_srcrel);
    hipLaunchKernelGGL(agg, dim3(25000), dim3(256), 0, stream, offsets, rec_srcrel, elr, projb, h_bias, out);
}

// Round 3
// 478.432 us; speedup vs baseline: 1.9811x; 1.2983x over previous
//
#include <hip/hip_runtime.h>
#include <hip/hip_bf16.h>

// HET relational attention layer.
//  K0 cast_inputs : inputs f32[100000,128] -> bf16 Ab[100096,128] (pad rows zeroed)
//  K1 build_wextT : W_extT bf16[576][128] = [proj cols 512 | el 32 | er 32]^T
//  K2 gemm_mfma   : proj(bf16)[N,512], elr(f32)[N,64] = Ab @ W_ext   (16x16x32 bf16 MFMA, no LDS)
//  CSR build      : zero -> count -> 2-level scan -> scatter (src*8+rel)
//  K_agg          : 1 wave per dst node; pass1 lane-parallel denom, pass2 lane=column.

#define NN 100000
#define NNP 100096            // padded to 782*128
#define NE 1600000
#define NH 4
#define INF_ 128
#define DH 16
#define NCOL 576
#define LEAKY 0.2f
#define NBLK_SCAN 98

typedef __hip_bfloat16 bf16;
typedef __attribute__((ext_vector_type(8))) short bf16x8;
typedef __attribute__((ext_vector_type(4))) float f32x4;

static __device__ __forceinline__ short f2bs(float x) {
    bf16 b = __float2bfloat16(x);
    return *reinterpret_cast<short*>(&b);
}

__global__ void cast_inputs(const float* __restrict__ in, short* __restrict__ Ab) {
    int tid = blockIdx.x * 256 + threadIdx.x;       // one per 8 elements
    if (tid >= NNP * INF_ / 8) return;
    int base = tid * 8;
    int n = base >> 7;
    bf16x8 v;
    if (n < NN) {
        float4 f0 = *(const float4*)&in[base];
        float4 f1 = *(const float4*)&in[base + 4];
        v[0] = f2bs(f0.x); v[1] = f2bs(f0.y); v[2] = f2bs(f0.z); v[3] = f2bs(f0.w);
        v[4] = f2bs(f1.x); v[5] = f2bs(f1.y); v[6] = f2bs(f1.z); v[7] = f2bs(f1.w);
    } else {
        v = (bf16x8)(short)0;
    }
    *(bf16x8*)&Ab[base] = v;
}

// wextT[c][i], c in [0,576), i in [0,128)
__global__ void build_wextT(const float* __restrict__ W, const float* __restrict__ al,
                            const float* __restrict__ ar, short* __restrict__ wextT) {
    int idx = blockIdx.x * 256 + threadIdx.x;
    if (idx >= NCOL * INF_) return;
    int c = idx / INF_, i = idx % INF_;
    float v;
    if (c < 512) {
        int r = c >> 6, rem = c & 63, h = rem >> 4, d = rem & 15;
        v = W[((r * NH + h) * INF_ + i) * DH + d];
    } else {
        int rh = c - 512;
        const float* a = al;
        if (rh >= 32) { rh -= 32; a = ar; }
        int r = rh >> 2, h = rh & 3;
        const float* wp = &W[((r * NH + h) * INF_ + i) * DH];
        const float* ap = &a[(r * NH + h) * DH];
        float s = 0.f;
        #pragma unroll
        for (int d = 0; d < DH; ++d) s += wp[d] * ap[d];
        v = s;
    }
    wextT[c * INF_ + i] = f2bs(v);
}

// Block = 4 waves; wave owns 32 rows x 64 cols. Grid (NNP/128, 9).
// A,B frags read straight from global (A is L3-resident, B is L1-resident).
__global__ __launch_bounds__(256) void gemm_mfma(
    const short* __restrict__ Ab, const short* __restrict__ WxT,
    bf16* __restrict__ projb, float* __restrict__ elr) {
    int t = threadIdx.x;
    int wave = t >> 6, lane = t & 63;
    int n0 = blockIdx.x * 128 + wave * 32;
    int c0 = blockIdx.y * 64;
    int g = lane >> 4, r = lane & 15;

    f32x4 acc[2][4] = {};
    #pragma unroll
    for (int ks = 0; ks < 4; ++ks) {
        int k0 = ks * 32 + g * 8;
        bf16x8 a0 = *(const bf16x8*)&Ab[(n0 + r) * INF_ + k0];
        bf16x8 a1 = *(const bf16x8*)&Ab[(n0 + 16 + r) * INF_ + k0];
        #pragma unroll
        for (int j = 0; j < 4; ++j) {
            bf16x8 b = *(const bf16x8*)&WxT[(c0 + j * 16 + r) * INF_ + k0];
            acc[0][j] = __builtin_amdgcn_mfma_f32_16x16x32_bf16(a0, b, acc[0][j], 0, 0, 0);
            acc[1][j] = __builtin_amdgcn_mfma_f32_16x16x32_bf16(a1, b, acc[1][j], 0, 0, 0);
        }
    }

    #pragma unroll
    for (int m = 0; m < 2; ++m) {
        #pragma unroll
        for (int j = 0; j < 4; ++j) {
            int n = n0 + m * 16 + g * 4 + j;
            if (n >= NN) continue;
            if (c0 < 512) {
                #pragma unroll
                for (int jf = 0; jf < 4; ++jf)
                    projb[n * 512 + c0 + jf * 16 + r] = __float2bfloat16(acc[m][jf][j]);
            } else {
                #pragma unroll
                for (int jf = 0; jf < 4; ++jf)
                    elr[n * 64 + jf * 16 + r] = acc[m][jf][j];
            }
        }
    }
}

__global__ void zero_counts(int* __restrict__ counts) {
    int i = blockIdx.x * 256 + threadIdx.x;
    if (i < NN) counts[i] = 0;
}

__global__ void count_edges(const int* __restrict__ dst, int* __restrict__ counts) {
    int e = blockIdx.x * 256 + threadIdx.x;
    if (e < NE) atomicAdd(&counts[dst[e]], 1);
}

__global__ __launch_bounds__(256) void scan_block(const int* __restrict__ counts,
                                                  int* __restrict__ offsets,
                                                  int* __restrict__ blockSums) {
    __shared__ int tsum[256];
    int b = blockIdx.x, t = threadIdx.x;
    int base = b * 1024 + t * 4;
    int v0 = (base + 0 < NN) ? counts[base + 0] : 0;
    int v1 = (base + 1 < NN) ? counts[base + 1] : 0;
    int v2 = (base + 2 < NN) ? counts[base + 2] : 0;
    int v3 = (base + 3 < NN) ? counts[base + 3] : 0;
    int own = v0 + v1 + v2 + v3;
    tsum[t] = own;
    __syncthreads();
    for (int st = 1; st < 256; st <<= 1) {
        int y = (t >= st) ? tsum[t - st] : 0;
        __syncthreads();
        tsum[t] += y;
        __syncthreads();
    }
    int excl = tsum[t] - own;
    if (base + 0 < NN) offsets[base + 0] = excl;
    if (base + 1 < NN) offsets[base + 1] = excl + v0;
    if (base + 2 < NN) offsets[base + 2] = excl + v0 + v1;
    if (base + 3 < NN) offsets[base + 3] = excl + v0 + v1 + v2;
    if (t == 255) blockSums[b] = tsum[255];
}

__global__ __launch_bounds__(128) void scan_top(const int* __restrict__ blockSums,
                                                int* __restrict__ blockOff) {
    __shared__ int sb[128];
    int t = threadIdx.x;
    int own = (t < NBLK_SCAN) ? blockSums[t] : 0;
    sb[t] = own;
    __syncthreads();
    for (int st = 1; st < 128; st <<= 1) {
        int y = (t >= st) ? sb[t - st] : 0;
        __syncthreads();
        sb[t] += y;
        __syncthreads();
    }
    blockOff[t] = sb[t] - own;
}

__global__ void scan_add(int* __restrict__ offsets, const int* __restrict__ blockOff,
                         int* __restrict__ cursor) {
    int i = blockIdx.x * 256 + threadIdx.x;
    if (i < NN) {
        int v = offsets[i] + blockOff[i >> 10];
        offsets[i] = v;
        cursor[i] = v;
    }
    if (i == 0) offsets[NN] = NE;
}

__global__ void scatter_edges(const int* __restrict__ src, const int* __restrict__ dst,
                              const int* __restrict__ rel, int* __restrict__ cursor,
                              int* __restrict__ rec_srcrel) {
    int e = blockIdx.x * 256 + threadIdx.x;
    if (e >= NE) return;
    int d = dst[e];
    int pos = atomicAdd(&cursor[d], 1);
    rec_srcrel[pos] = src[e] * 8 + rel[e];
}

__global__ __launch_bounds__(256) void agg(
    const int* __restrict__ offsets, const int* __restrict__ rec_srcrel,
    const float* __restrict__ elr, const bf16* __restrict__ projb,
    const float* __restrict__ bias, float* __restrict__ out) {
    int d = blockIdx.x * 4 + (threadIdx.x >> 6);
    if (d >= NN) return;
    int lane = threadIdx.x & 63;
    int off = offsets[d], end = offsets[d + 1];

    float dsum0 = 0.f, dsum1 = 0.f, dsum2 = 0.f, dsum3 = 0.f;
    for (int i = off + lane; i < end; i += 64) {
        int sr = rec_srcrel[i];
        int s = sr >> 3, r = sr & 7;
        float4 el4 = *(const float4*)&elr[s * 64 + r * 4];
        float4 er4 = *(const float4*)&elr[d * 64 + 32 + r * 4];
        float x;
        x = el4.x + er4.x; x = x > 0.f ? x : LEAKY * x; dsum0 += __expf(x);
        x = el4.y + er4.y; x = x > 0.f ? x : LEAKY * x; dsum1 += __expf(x);
        x = el4.z + er4.z; x = x > 0.f ? x : LEAKY * x; dsum2 += __expf(x);
        x = el4.w + er4.w; x = x > 0.f ? x : LEAKY * x; dsum3 += __expf(x);
    }
    #pragma unroll
    for (int m = 32; m; m >>= 1) {
        dsum0 += __shfl_xor(dsum0, m, 64);
        dsum1 += __shfl_xor(dsum1, m, 64);
        dsum2 += __shfl_xor(dsum2, m, 64);
        dsum3 += __shfl_xor(dsum3, m, 64);
    }

    int c = lane, h = c >> 4;
    float dh = (h == 0) ? dsum0 : (h == 1) ? dsum1 : (h == 2) ? dsum2 : dsum3;
    float rd = 1.0f / dh;
    float acc = 0.f;
    for (int i = off; i < end; ++i) {
        int sr = rec_srcrel[i];
        int s = sr >> 3, r = sr & 7;
        float el = elr[s * 64 + r * 4 + h];
        float er = elr[d * 64 + 32 + r * 4 + h];
        float x = el + er;
        x = x > 0.f ? x : LEAKY * x;
        float alpha = __expf(x) * rd;
        acc += alpha * __bfloat162float(projb[sr * 64 + c]);
    }
    out[d * 64 + c] = acc + bias[c];
}

extern "C" void kernel_launch(void* const* d_in, const int* in_sizes, int n_in,
                              void* d_out, int out_size, void* d_ws, size_t ws_size,
                              hipStream_t stream) {
    const float* inputs = (const float*)d_in[0];
    const float* convw  = (const float*)d_in[1];
    const float* attn_l = (const float*)d_in[2];
    const float* attn_r = (const float*)d_in[3];
    const float* h_bias = (const float*)d_in[4];
    const int*   src    = (const int*)d_in[5];
    const int*   dst    = (const int*)d_in[6];
    const int*   rel    = (const int*)d_in[7];
    float* out = (float*)d_out;

    char* ws = (char*)d_ws;
    size_t o = 0;
    // Region 0: Ab during GEMM phase, then CSR scratch (strictly after gemm on stream).
    short* Ab = (short*)(ws + o);
    int* offsets   = (int*)(ws + o);                  //   400,128 B
    int* cursor    = (int*)(ws + o + 400128);         //   400,000 B
    int* blockSums = (int*)(ws + o + 800128);         //       512 B
    int* blockOff  = (int*)(ws + o + 800640);         //       512 B
    int* rec_srcrel= (int*)(ws + o + 801152);         // 6,400,000 B  (7.2MB < 25.6MB)
    o += (size_t)NNP * INF_ * 2;                      // 25,624,576 B
    bf16* projb = (bf16*)(ws + o);  o += 102400000ull;
    float* elr  = (float*)(ws + o); o += 25600000ull;
    short* wextT = (short*)(ws + o); o += NCOL * INF_ * 2;

    hipLaunchKernelGGL(cast_inputs, dim3(NNP * INF_ / 8 / 256), dim3(256), 0, stream, inputs, Ab);
    hipLaunchKernelGGL(build_wextT, dim3(288), dim3(256), 0, stream, convw, attn_l, attn_r, wextT);
    hipLaunchKernelGGL(gemm_mfma, dim3(NNP / 128, 9), dim3(256), 0, stream, Ab, wextT, projb, elr);
    hipLaunchKernelGGL(zero_counts, dim3(391), dim3(256), 0, stream, cursor);
    hipLaunchKernelGGL(count_edges, dim3(6250), dim3(256), 0, stream, dst, cursor);
    hipLaunchKernelGGL(scan_block, dim3(NBLK_SCAN), dim3(256), 0, stream, cursor, offsets, blockSums);
    hipLaunchKernelGGL(scan_top, dim3(1), dim3(128), 0, stream, blockSums, blockOff);
    hipLaunchKernelGGL(scan_add, dim3(391), dim3(256), 0, stream, offsets, blockOff, cursor);
    hipLaunchKernelGGL(scatter_edges, dim3(6250), dim3(256), 0, stream, src, dst, rel, cursor, rec_srcrel);
    hipLaunchKernelGGL(agg, dim3(25000), dim3(256), 0, stream, offsets, rec_srcrel, elr, projb, h_bias, out);
}

// Round 4
// 361.604 us; speedup vs baseline: 2.6212x; 1.3231x over previous
//
#include <hip/hip_runtime.h>
#include <hip/hip_bf16.h>

// HET relational attention layer.
//  K1 build_wextT : W_extT bf16[576][128] = [proj cols 512 | el 32 | er 32]^T
//  K2 gemm_direct : proj(bf16)[N,512], elr(f32)[N,64] = A(f32, converted in-reg) @ W_ext
//                   (16x16x32 bf16 MFMA; A read once per block; 9 col-blocks looped in-kernel)
//  CSR build      : zero -> count -> 2-level scan -> scatter (src*8+rel)
//  K_agg          : 1 wave per dst node. Fast path (deg<=64): lane-parallel exp -> LDS stash,
//                   serial column pass = 2 LDS broadcast reads + 1 gather + fma, unrolled x4,
//                   denom folded into the loop. Slow path (deg>64): old two-pass code.

#define NN 100000
#define NNP 100096            // 782*128
#define NE 1600000
#define NH 4
#define INF_ 128
#define DH 16
#define NCOL 576
#define LEAKY 0.2f
#define NBLK_SCAN 98

typedef __hip_bfloat16 bf16;
typedef __attribute__((ext_vector_type(8))) short bf16x8;
typedef __attribute__((ext_vector_type(4))) float f32x4;

static __device__ __forceinline__ short f2bs(float x) {
    bf16 b = __float2bfloat16(x);
    return *reinterpret_cast<short*>(&b);
}

// wextT[c][i], c in [0,576), i in [0,128)
__global__ void build_wextT(const float* __restrict__ W, const float* __restrict__ al,
                            const float* __restrict__ ar, short* __restrict__ wextT) {
    int idx = blockIdx.x * 256 + threadIdx.x;
    if (idx >= NCOL * INF_) return;
    int c = idx / INF_, i = idx % INF_;
    float v;
    if (c < 512) {
        int r = c >> 6, rem = c & 63, h = rem >> 4, d = rem & 15;
        v = W[((r * NH + h) * INF_ + i) * DH + d];
    } else {
        int rh = c - 512;
        const float* a = al;
        if (rh >= 32) { rh -= 32; a = ar; }
        int r = rh >> 2, h = rh & 3;
        const float* wp = &W[((r * NH + h) * INF_ + i) * DH];
        const float* ap = &a[(r * NH + h) * DH];
        float s = 0.f;
        #pragma unroll
        for (int d = 0; d < DH; ++d) s += wp[d] * ap[d];
        v = s;
    }
    wextT[c * INF_ + i] = f2bs(v);
}

// Block = 4 waves; wave owns 32 rows. All 576 cols computed per block (A read once).
__global__ __launch_bounds__(256) void gemm_direct(
    const float* __restrict__ A, const short* __restrict__ WxT,
    bf16* __restrict__ projb, float* __restrict__ elr) {
    int t = threadIdx.x;
    int wave = t >> 6, lane = t & 63;
    int n0 = blockIdx.x * 128 + wave * 32;
    int g = lane >> 4, r = lane & 15;

    // Preload + convert A fragments: m in {0,1}, ks in 0..3
    bf16x8 afr[2][4];
    #pragma unroll
    for (int m = 0; m < 2; ++m) {
        int row = n0 + m * 16 + r;
        #pragma unroll
        for (int ks = 0; ks < 4; ++ks) {
            int k0 = ks * 32 + g * 8;
            bf16x8 v;
            if (row < NN) {
                float4 f0 = *(const float4*)&A[row * INF_ + k0];
                float4 f1 = *(const float4*)&A[row * INF_ + k0 + 4];
                v[0] = f2bs(f0.x); v[1] = f2bs(f0.y); v[2] = f2bs(f0.z); v[3] = f2bs(f0.w);
                v[4] = f2bs(f1.x); v[5] = f2bs(f1.y); v[6] = f2bs(f1.z); v[7] = f2bs(f1.w);
            } else {
                v = (bf16x8)(short)0;
            }
            afr[m][ks] = v;
        }
    }

    for (int cb = 0; cb < 9; ++cb) {
        int c0 = cb * 64;
        f32x4 acc[2][4] = {};
        #pragma unroll
        for (int ks = 0; ks < 4; ++ks) {
            int k0 = ks * 32 + g * 8;
            #pragma unroll
            for (int j = 0; j < 4; ++j) {
                bf16x8 b = *(const bf16x8*)&WxT[(c0 + j * 16 + r) * INF_ + k0];
                acc[0][j] = __builtin_amdgcn_mfma_f32_16x16x32_bf16(afr[0][ks], b, acc[0][j], 0, 0, 0);
                acc[1][j] = __builtin_amdgcn_mfma_f32_16x16x32_bf16(afr[1][ks], b, acc[1][j], 0, 0, 0);
            }
        }
        #pragma unroll
        for (int m = 0; m < 2; ++m) {
            #pragma unroll
            for (int j = 0; j < 4; ++j) {
                int n = n0 + m * 16 + g * 4 + j;
                if (n >= NN) continue;
                if (c0 < 512) {
                    #pragma unroll
                    for (int jf = 0; jf < 4; ++jf)
                        projb[n * 512 + c0 + jf * 16 + r] = __float2bfloat16(acc[m][jf][j]);
                } else {
                    #pragma unroll
                    for (int jf = 0; jf < 4; ++jf)
                        elr[n * 64 + jf * 16 + r] = acc[m][jf][j];
                }
            }
        }
    }
}

__global__ void zero_counts(int* __restrict__ counts) {
    int i = blockIdx.x * 256 + threadIdx.x;
    if (i < NN) counts[i] = 0;
}

__global__ void count_edges(const int* __restrict__ dst, int* __restrict__ counts) {
    int e = blockIdx.x * 256 + threadIdx.x;
    if (e < NE) atomicAdd(&counts[dst[e]], 1);
}

__global__ __launch_bounds__(256) void scan_block(const int* __restrict__ counts,
                                                  int* __restrict__ offsets,
                                                  int* __restrict__ blockSums) {
    __shared__ int tsum[256];
    int b = blockIdx.x, t = threadIdx.x;
    int base = b * 1024 + t * 4;
    int v0 = (base + 0 < NN) ? counts[base + 0] : 0;
    int v1 = (base + 1 < NN) ? counts[base + 1] : 0;
    int v2 = (base + 2 < NN) ? counts[base + 2] : 0;
    int v3 = (base + 3 < NN) ? counts[base + 3] : 0;
    int own = v0 + v1 + v2 + v3;
    tsum[t] = own;
    __syncthreads();
    for (int st = 1; st < 256; st <<= 1) {
        int y = (t >= st) ? tsum[t - st] : 0;
        __syncthreads();
        tsum[t] += y;
        __syncthreads();
    }
    int excl = tsum[t] - own;
    if (base + 0 < NN) offsets[base + 0] = excl;
    if (base + 1 < NN) offsets[base + 1] = excl + v0;
    if (base + 2 < NN) offsets[base + 2] = excl + v0 + v1;
    if (base + 3 < NN) offsets[base + 3] = excl + v0 + v1 + v2;
    if (t == 255) blockSums[b] = tsum[255];
}

__global__ __launch_bounds__(128) void scan_top(const int* __restrict__ blockSums,
                                                int* __restrict__ blockOff) {
    __shared__ int sb[128];
    int t = threadIdx.x;
    int own = (t < NBLK_SCAN) ? blockSums[t] : 0;
    sb[t] = own;
    __syncthreads();
    for (int st = 1; st < 128; st <<= 1) {
        int y = (t >= st) ? sb[t - st] : 0;
        __syncthreads();
        sb[t] += y;
        __syncthreads();
    }
    blockOff[t] = sb[t] - own;
}

__global__ void scan_add(int* __restrict__ offsets, const int* __restrict__ blockOff,
                         int* __restrict__ cursor) {
    int i = blockIdx.x * 256 + threadIdx.x;
    if (i < NN) {
        int v = offsets[i] + blockOff[i >> 10];
        offsets[i] = v;
        cursor[i] = v;
    }
    if (i == 0) offsets[NN] = NE;
}

__global__ void scatter_edges(const int* __restrict__ src, const int* __restrict__ dst,
                              const int* __restrict__ rel, int* __restrict__ cursor,
                              int* __restrict__ rec_srcrel) {
    int e = blockIdx.x * 256 + threadIdx.x;
    if (e >= NE) return;
    int d = dst[e];
    int pos = atomicAdd(&cursor[d], 1);
    rec_srcrel[pos] = src[e] * 8 + rel[e];
}

__global__ __launch_bounds__(256) void agg(
    const int* __restrict__ offsets, const int* __restrict__ rec_srcrel,
    const float* __restrict__ elr, const bf16* __restrict__ projb,
    const float* __restrict__ bias, float* __restrict__ out) {
    __shared__ float s_alpha[4][64][4];   // [wave][slot][head] unnormalized exp
    __shared__ int   s_rec[4][64];
    __shared__ float s_er[4][32];
    int wv = threadIdx.x >> 6, lane = threadIdx.x & 63;
    int d = blockIdx.x * 4 + wv;
    if (d >= NN) return;                  // wave-uniform; no cross-wave barriers used
    int off = offsets[d], end = offsets[d + 1];
    int deg = end - off;
    int c = lane, h = c >> 4;

    // preload this node's 32 er values (wave-private LDS)
    if (lane < 32) s_er[wv][lane] = elr[d * 64 + 32 + lane];
    __builtin_amdgcn_wave_barrier();
    asm volatile("s_waitcnt lgkmcnt(0)" ::: "memory");

    float res;
    if (deg == 0) {
        res = 0.f;
    } else if (deg <= 64) {
        // pass A: one edge per lane, compute 4 exps once, stash in LDS
        int i = off + lane;
        float e0 = 0.f, e1 = 0.f, e2 = 0.f, e3 = 0.f;
        int rec = 0;
        if (i < end) {
            rec = rec_srcrel[i];
            int s = rec >> 3, r = rec & 7;
            float4 el4 = *(const float4*)&elr[s * 64 + r * 4];
            float x;
            x = el4.x + s_er[wv][r * 4 + 0]; x = x > 0.f ? x : LEAKY * x; e0 = __expf(x);
            x = el4.y + s_er[wv][r * 4 + 1]; x = x > 0.f ? x : LEAKY * x; e1 = __expf(x);
            x = el4.z + s_er[wv][r * 4 + 2]; x = x > 0.f ? x : LEAKY * x; e2 = __expf(x);
            x = el4.w + s_er[wv][r * 4 + 3]; x = x > 0.f ? x : LEAKY * x; e3 = __expf(x);
        }
        s_rec[wv][lane] = rec;
        float4 a4 = make_float4(e0, e1, e2, e3);
        *(float4*)&s_alpha[wv][lane][0] = a4;
        __builtin_amdgcn_wave_barrier();
        asm volatile("s_waitcnt lgkmcnt(0)" ::: "memory");

        // pass B: lane owns column c; serial over edges, unrolled x4 for MLP
        float acc = 0.f, dsum = 0.f;
        int j = 0;
        for (; j + 4 <= deg; j += 4) {
            int sr0 = s_rec[wv][j + 0], sr1 = s_rec[wv][j + 1];
            int sr2 = s_rec[wv][j + 2], sr3 = s_rec[wv][j + 3];
            float a0 = s_alpha[wv][j + 0][h], a1 = s_alpha[wv][j + 1][h];
            float a2 = s_alpha[wv][j + 2][h], a3 = s_alpha[wv][j + 3][h];
            float v0 = __bfloat162float(projb[sr0 * 64 + c]);
            float v1 = __bfloat162float(projb[sr1 * 64 + c]);
            float v2 = __bfloat162float(projb[sr2 * 64 + c]);
            float v3 = __bfloat162float(projb[sr3 * 64 + c]);
            dsum += (a0 + a1) + (a2 + a3);
            acc = fmaf(a0, v0, acc);
            acc = fmaf(a1, v1, acc);
            acc = fmaf(a2, v2, acc);
            acc = fmaf(a3, v3, acc);
        }
        for (; j < deg; ++j) {
            int sr = s_rec[wv][j];
            float a = s_alpha[wv][j][h];
            float v = __bfloat162float(projb[sr * 64 + c]);
            dsum += a;
            acc = fmaf(a, v, acc);
        }
        res = acc / dsum;
    } else {
        // slow path (deg > 64): two-pass recompute (rare with Poisson(16) degrees)
        float dsum0 = 0.f, dsum1 = 0.f, dsum2 = 0.f, dsum3 = 0.f;
        for (int i = off + lane; i < end; i += 64) {
            int sr = rec_srcrel[i];
            int s = sr >> 3, r = sr & 7;
            float4 el4 = *(const float4*)&elr[s * 64 + r * 4];
            float x;
            x = el4.x + s_er[wv][r * 4 + 0]; x = x > 0.f ? x : LEAKY * x; dsum0 += __expf(x);
            x = el4.y + s_er[wv][r * 4 + 1]; x = x > 0.f ? x : LEAKY * x; dsum1 += __expf(x);
            x = el4.z + s_er[wv][r * 4 + 2]; x = x > 0.f ? x : LEAKY * x; dsum2 += __expf(x);
            x = el4.w + s_er[wv][r * 4 + 3]; x = x > 0.f ? x : LEAKY * x; dsum3 += __expf(x);
        }
        #pragma unroll
        for (int m = 32; m; m >>= 1) {
            dsum0 += __shfl_xor(dsum0, m, 64);
            dsum1 += __shfl_xor(dsum1, m, 64);
            dsum2 += __shfl_xor(dsum2, m, 64);
            dsum3 += __shfl_xor(dsum3, m, 64);
        }
        float dh = (h == 0) ? dsum0 : (h == 1) ? dsum1 : (h == 2) ? dsum2 : dsum3;
        float rd = 1.0f / dh;
        float acc = 0.f;
        for (int i = off; i < end; ++i) {
            int sr = rec_srcrel[i];
            int s = sr >> 3, r = sr & 7;
            float x = elr[s * 64 + r * 4 + h] + s_er[wv][r * 4 + h];
            x = x > 0.f ? x : LEAKY * x;
            acc = fmaf(__expf(x) * rd, __bfloat162float(projb[sr * 64 + c]), acc);
        }
        res = acc;
    }
    out[d * 64 + c] = res + bias[c];
}

extern "C" void kernel_launch(void* const* d_in, const int* in_sizes, int n_in,
                              void* d_out, int out_size, void* d_ws, size_t ws_size,
                              hipStream_t stream) {
    const float* inputs = (const float*)d_in[0];
    const float* convw  = (const float*)d_in[1];
    const float* attn_l = (const float*)d_in[2];
    const float* attn_r = (const float*)d_in[3];
    const float* h_bias = (const float*)d_in[4];
    const int*   src    = (const int*)d_in[5];
    const int*   dst    = (const int*)d_in[6];
    const int*   rel    = (const int*)d_in[7];
    float* out = (float*)d_out;

    char* ws = (char*)d_ws;
    size_t o = 0;
    bf16* projb = (bf16*)(ws + o);  o += 102400000ull;
    float* elr  = (float*)(ws + o); o += 25600000ull;
    short* wextT = (short*)(ws + o); o += 147456;
    int* offsets    = (int*)(ws + o); o += 400128;
    int* cursor     = (int*)(ws + o); o += 400000;
    int* blockSums  = (int*)(ws + o); o += 512;
    int* blockOff   = (int*)(ws + o); o += 512;
    int* rec_srcrel = (int*)(ws + o); o += 6400000ull;

    hipLaunchKernelGGL(build_wextT, dim3(288), dim3(256), 0, stream, convw, attn_l, attn_r, wextT);
    hipLaunchKernelGGL(gemm_direct, dim3(NNP / 128), dim3(256), 0, stream, inputs, wextT, projb, elr);
    hipLaunchKernelGGL(zero_counts, dim3(391), dim3(256), 0, stream, cursor);
    hipLaunchKernelGGL(count_edges, dim3(6250), dim3(256), 0, stream, dst, cursor);
    hipLaunchKernelGGL(scan_block, dim3(NBLK_SCAN), dim3(256), 0, stream, cursor, offsets, blockSums);
    hipLaunchKernelGGL(scan_top, dim3(1), dim3(128), 0, stream, blockSums, blockOff);
    hipLaunchKernelGGL(scan_add, dim3(391), dim3(256), 0, stream, offsets, blockOff, cursor);
    hipLaunchKernelGGL(scatter_edges, dim3(6250), dim3(256), 0, stream, src, dst, rel, cursor, rec_srcrel);
    hipLaunchKernelGGL(agg, dim3(25000), dim3(256), 0, stream, offsets, rec_srcrel, elr, projb, h_bias, out);
}

// Round 5
// 217.181 us; speedup vs baseline: 4.3642x; 1.6650x over previous
//
#include <hip/hip_runtime.h>
#include <hip/hip_bf16.h>

// HET relational attention layer.
//  K1 build_wextT   : W_extT bf16[576][128] = [proj cols 512 | el 32 | er 32]^T
//  K2 gemm_direct   : proj(bf16)[N,512], elr(f32)[N,64] = A(f32->bf16 in-reg) @ W_ext (MFMA)
//  CSR build (bucketed, low write-amplification):
//    zero_buckets   : bucketCount = 0
//    bucket_count   : per-bucket edge histogram (bucket = dst>>8, 391 buckets)
//    scan_buckets   : bucketOff = exclusive scan; gCursor = bucketOff
//    bucket_scatter : block histograms 4096 edges in LDS, one global atomic per bucket
//                     per block reserves a contiguous run; writes packed recs in runs.
//    exact_place    : one block per bucket; LDS hist over 256 nodes -> scan -> writes
//                     global CSR offsets + scatters recs to exact pos (16KB window).
//  K_agg            : 1 wave per dst node; fast path deg<=64: exp once per edge -> LDS,
//                     serial column pass unrolled x8; denom folded in.

#define NN 100000
#define NNP 100096            // 782*128
#define NE 1600000
#define NH 4
#define INF_ 128
#define DH 16
#define NCOL 576
#define LEAKY 0.2f
#define NBUCK 391             // ceil(100000/256)
#define BSHIFT 8
#define CHUNK 4096            // edges per bucket_count/bucket_scatter block

typedef __hip_bfloat16 bf16;
typedef __attribute__((ext_vector_type(8))) short bf16x8;
typedef __attribute__((ext_vector_type(4))) float f32x4;

static __device__ __forceinline__ short f2bs(float x) {
    bf16 b = __float2bfloat16(x);
    return *reinterpret_cast<short*>(&b);
}

__global__ void build_wextT(const float* __restrict__ W, const float* __restrict__ al,
                            const float* __restrict__ ar, short* __restrict__ wextT) {
    int idx = blockIdx.x * 256 + threadIdx.x;
    if (idx >= NCOL * INF_) return;
    int c = idx / INF_, i = idx % INF_;
    float v;
    if (c < 512) {
        int r = c >> 6, rem = c & 63, h = rem >> 4, d = rem & 15;
        v = W[((r * NH + h) * INF_ + i) * DH + d];
    } else {
        int rh = c - 512;
        const float* a = al;
        if (rh >= 32) { rh -= 32; a = ar; }
        int r = rh >> 2, h = rh & 3;
        const float* wp = &W[((r * NH + h) * INF_ + i) * DH];
        const float* ap = &a[(r * NH + h) * DH];
        float s = 0.f;
        #pragma unroll
        for (int d = 0; d < DH; ++d) s += wp[d] * ap[d];
        v = s;
    }
    wextT[c * INF_ + i] = f2bs(v);
}

__global__ __launch_bounds__(256) void gemm_direct(
    const float* __restrict__ A, const short* __restrict__ WxT,
    bf16* __restrict__ projb, float* __restrict__ elr) {
    int t = threadIdx.x;
    int wave = t >> 6, lane = t & 63;
    int n0 = blockIdx.x * 128 + wave * 32;
    int g = lane >> 4, r = lane & 15;

    bf16x8 afr[2][4];
    #pragma unroll
    for (int m = 0; m < 2; ++m) {
        int row = n0 + m * 16 + r;
        #pragma unroll
        for (int ks = 0; ks < 4; ++ks) {
            int k0 = ks * 32 + g * 8;
            bf16x8 v;
            if (row < NN) {
                float4 f0 = *(const float4*)&A[row * INF_ + k0];
                float4 f1 = *(const float4*)&A[row * INF_ + k0 + 4];
                v[0] = f2bs(f0.x); v[1] = f2bs(f0.y); v[2] = f2bs(f0.z); v[3] = f2bs(f0.w);
                v[4] = f2bs(f1.x); v[5] = f2bs(f1.y); v[6] = f2bs(f1.z); v[7] = f2bs(f1.w);
            } else {
                v = (bf16x8)(short)0;
            }
            afr[m][ks] = v;
        }
    }

    for (int cb = 0; cb < 9; ++cb) {
        int c0 = cb * 64;
        f32x4 acc[2][4] = {};
        #pragma unroll
        for (int ks = 0; ks < 4; ++ks) {
            int k0 = ks * 32 + g * 8;
            #pragma unroll
            for (int j = 0; j < 4; ++j) {
                bf16x8 b = *(const bf16x8*)&WxT[(c0 + j * 16 + r) * INF_ + k0];
                acc[0][j] = __builtin_amdgcn_mfma_f32_16x16x32_bf16(afr[0][ks], b, acc[0][j], 0, 0, 0);
                acc[1][j] = __builtin_amdgcn_mfma_f32_16x16x32_bf16(afr[1][ks], b, acc[1][j], 0, 0, 0);
            }
        }
        #pragma unroll
        for (int m = 0; m < 2; ++m) {
            #pragma unroll
            for (int j = 0; j < 4; ++j) {
                int n = n0 + m * 16 + g * 4 + j;
                if (n >= NN) continue;
                if (c0 < 512) {
                    #pragma unroll
                    for (int jf = 0; jf < 4; ++jf)
                        projb[n * 512 + c0 + jf * 16 + r] = __float2bfloat16(acc[m][jf][j]);
                } else {
                    #pragma unroll
                    for (int jf = 0; jf < 4; ++jf)
                        elr[n * 64 + jf * 16 + r] = acc[m][jf][j];
                }
            }
        }
    }
}

__global__ void zero_buckets(int* __restrict__ bucketCount) {
    int i = blockIdx.x * 256 + threadIdx.x;
    if (i < NBUCK) bucketCount[i] = 0;
}

__global__ __launch_bounds__(256) void bucket_count(const int* __restrict__ dst,
                                                    int* __restrict__ bucketCount) {
    __shared__ int hist[NBUCK];
    int t = threadIdx.x;
    for (int i = t; i < NBUCK; i += 256) hist[i] = 0;
    __syncthreads();
    int base = blockIdx.x * CHUNK;
    #pragma unroll
    for (int j = 0; j < CHUNK / 256; ++j) {
        int e = base + j * 256 + t;
        if (e < NE) atomicAdd(&hist[dst[e] >> BSHIFT], 1);
    }
    __syncthreads();
    for (int i = t; i < NBUCK; i += 256) {
        int v = hist[i];
        if (v) atomicAdd(&bucketCount[i], v);
    }
}

__global__ __launch_bounds__(256) void scan_buckets(const int* __restrict__ bucketCount,
                                                    int* __restrict__ bucketOff,
                                                    int* __restrict__ gCursor) {
    __shared__ int tsum[256];
    int t = threadIdx.x;
    int i0 = 2 * t, i1 = 2 * t + 1;
    int a = (i0 < NBUCK) ? bucketCount[i0] : 0;
    int b = (i1 < NBUCK) ? bucketCount[i1] : 0;
    int own = a + b;
    tsum[t] = own;
    __syncthreads();
    for (int st = 1; st < 256; st <<= 1) {
        int y = (t >= st) ? tsum[t - st] : 0;
        __syncthreads();
        tsum[t] += y;
        __syncthreads();
    }
    int excl = tsum[t] - own;
    if (i0 <= NBUCK) { bucketOff[i0] = excl; if (i0 < NBUCK) gCursor[i0] = excl; }
    if (i1 <= NBUCK) { bucketOff[i1] = excl + a; if (i1 < NBUCK) gCursor[i1] = excl + a; }
}

// rec32 = (dst&255)<<20 | (src*8+rel)   [src*8+rel < 2^20]
__global__ __launch_bounds__(256) void bucket_scatter(
    const int* __restrict__ src, const int* __restrict__ dst, const int* __restrict__ rel,
    int* __restrict__ gCursor, int* __restrict__ pairbuf) {
    __shared__ int hist[NBUCK];
    int t = threadIdx.x;
    for (int i = t; i < NBUCK; i += 256) hist[i] = 0;
    __syncthreads();
    int base = blockIdx.x * CHUNK;
    #pragma unroll
    for (int j = 0; j < CHUNK / 256; ++j) {
        int e = base + j * 256 + t;
        if (e < NE) atomicAdd(&hist[dst[e] >> BSHIFT], 1);
    }
    __syncthreads();
    for (int i = t; i < NBUCK; i += 256) {
        int v = hist[i];
        hist[i] = v ? atomicAdd(&gCursor[i], v) : 0;   // hist becomes global write cursor
    }
    __syncthreads();
    #pragma unroll
    for (int j = 0; j < CHUNK / 256; ++j) {
        int e = base + j * 256 + t;
        if (e < NE) {
            int d = dst[e];
            int b = d >> BSHIFT;
            int rec = ((d & 255) << 20) | (src[e] * 8 + rel[e]);
            int pos = atomicAdd(&hist[b], 1);
            pairbuf[pos] = rec;
        }
    }
}

// One block per bucket: per-node counts -> scan -> global offsets + exact scatter.
__global__ __launch_bounds__(256) void exact_place(
    const int* __restrict__ bucketOff, const int* __restrict__ pairbuf,
    int* __restrict__ offsets, int* __restrict__ rec_srcrel) {
    __shared__ int hist[256];
    __shared__ int tsum[256];
    int b = blockIdx.x, t = threadIdx.x;
    int start = bucketOff[b], cnt = bucketOff[b + 1] - start;
    hist[t] = 0;
    __syncthreads();
    for (int i = t; i < cnt; i += 256) atomicAdd(&hist[pairbuf[start + i] >> 20], 1);
    __syncthreads();
    int own = hist[t];
    tsum[t] = own;
    __syncthreads();
    for (int st = 1; st < 256; st <<= 1) {
        int y = (t >= st) ? tsum[t - st] : 0;
        __syncthreads();
        tsum[t] += y;
        __syncthreads();
    }
    int excl = start + tsum[t] - own;
    int node = b * 256 + t;
    if (node <= NN) offsets[node] = excl;   // node==NN gets NE (trailing zero-count slots)
    __syncthreads();
    hist[t] = excl;                          // reuse as exact-position cursor
    __syncthreads();
    for (int i = t; i < cnt; i += 256) {
        int rec = pairbuf[start + i];
        int pos = atomicAdd(&hist[rec >> 20], 1);
        rec_srcrel[pos] = rec & 0xFFFFF;
    }
}

__global__ __launch_bounds__(256) void agg(
    const int* __restrict__ offsets, const int* __restrict__ rec_srcrel,
    const float* __restrict__ elr, const bf16* __restrict__ projb,
    const float* __restrict__ bias, float* __restrict__ out) {
    __shared__ float s_alpha[4][64][4];
    __shared__ int   s_rec[4][64];
    __shared__ float s_er[4][32];
    int wv = threadIdx.x >> 6, lane = threadIdx.x & 63;
    int d = blockIdx.x * 4 + wv;
    if (d >= NN) return;
    int off = offsets[d], end = offsets[d + 1];
    int deg = end - off;
    int c = lane, h = c >> 4;

    if (lane < 32) s_er[wv][lane] = elr[d * 64 + 32 + lane];
    __builtin_amdgcn_wave_barrier();
    asm volatile("s_waitcnt lgkmcnt(0)" ::: "memory");

    float res;
    if (deg == 0) {
        res = 0.f;
    } else if (deg <= 64) {
        int i = off + lane;
        float e0 = 0.f, e1 = 0.f, e2 = 0.f, e3 = 0.f;
        int rec = 0;
        if (i < end) {
            rec = rec_srcrel[i];
            int s = rec >> 3, r = rec & 7;
            float4 el4 = *(const float4*)&elr[s * 64 + r * 4];
            float x;
            x = el4.x + s_er[wv][r * 4 + 0]; x = x > 0.f ? x : LEAKY * x; e0 = __expf(x);
            x = el4.y + s_er[wv][r * 4 + 1]; x = x > 0.f ? x : LEAKY * x; e1 = __expf(x);
            x = el4.z + s_er[wv][r * 4 + 2]; x = x > 0.f ? x : LEAKY * x; e2 = __expf(x);
            x = el4.w + s_er[wv][r * 4 + 3]; x = x > 0.f ? x : LEAKY * x; e3 = __expf(x);
        }
        s_rec[wv][lane] = rec;
        *(float4*)&s_alpha[wv][lane][0] = make_float4(e0, e1, e2, e3);
        __builtin_amdgcn_wave_barrier();
        asm volatile("s_waitcnt lgkmcnt(0)" ::: "memory");

        float acc = 0.f, dsum = 0.f;
        int j = 0;
        for (; j + 8 <= deg; j += 8) {
            float vv[8], aa[8];
            #pragma unroll
            for (int u = 0; u < 8; ++u) {
                int sr = s_rec[wv][j + u];
                aa[u] = s_alpha[wv][j + u][h];
                vv[u] = __bfloat162float(projb[sr * 64 + c]);
            }
            #pragma unroll
            for (int u = 0; u < 8; ++u) {
                dsum += aa[u];
                acc = fmaf(aa[u], vv[u], acc);
            }
        }
        for (; j < deg; ++j) {
            int sr = s_rec[wv][j];
            float a = s_alpha[wv][j][h];
            float v = __bfloat162float(projb[sr * 64 + c]);
            dsum += a;
            acc = fmaf(a, v, acc);
        }
        res = acc / dsum;
    } else {
        float dsum0 = 0.f, dsum1 = 0.f, dsum2 = 0.f, dsum3 = 0.f;
        for (int i = off + lane; i < end; i += 64) {
            int sr = rec_srcrel[i];
            int s = sr >> 3, r = sr & 7;
            float4 el4 = *(const float4*)&elr[s * 64 + r * 4];
            float x;
            x = el4.x + s_er[wv][r * 4 + 0]; x = x > 0.f ? x : LEAKY * x; dsum0 += __expf(x);
            x = el4.y + s_er[wv][r * 4 + 1]; x = x > 0.f ? x : LEAKY * x; dsum1 += __expf(x);
            x = el4.z + s_er[wv][r * 4 + 2]; x = x > 0.f ? x : LEAKY * x; dsum2 += __expf(x);
            x = el4.w + s_er[wv][r * 4 + 3]; x = x > 0.f ? x : LEAKY * x; dsum3 += __expf(x);
        }
        #pragma unroll
        for (int m = 32; m; m >>= 1) {
            dsum0 += __shfl_xor(dsum0, m, 64);
            dsum1 += __shfl_xor(dsum1, m, 64);
            dsum2 += __shfl_xor(dsum2, m, 64);
            dsum3 += __shfl_xor(dsum3, m, 64);
        }
        float dh = (h == 0) ? dsum0 : (h == 1) ? dsum1 : (h == 2) ? dsum2 : dsum3;
        float rd = 1.0f / dh;
        float acc = 0.f;
        for (int i = off; i < end; ++i) {
            int sr = rec_srcrel[i];
            int s = sr >> 3, r = sr & 7;
            float x = elr[s * 64 + r * 4 + h] + s_er[wv][r * 4 + h];
            x = x > 0.f ? x : LEAKY * x;
            acc = fmaf(__expf(x) * rd, __bfloat162float(projb[sr * 64 + c]), acc);
        }
        res = acc;
    }
    out[d * 64 + c] = res + bias[c];
}

extern "C" void kernel_launch(void* const* d_in, const int* in_sizes, int n_in,
                              void* d_out, int out_size, void* d_ws, size_t ws_size,
                              hipStream_t stream) {
    const float* inputs = (const float*)d_in[0];
    const float* convw  = (const float*)d_in[1];
    const float* attn_l = (const float*)d_in[2];
    const float* attn_r = (const float*)d_in[3];
    const float* h_bias = (const float*)d_in[4];
    const int*   src    = (const int*)d_in[5];
    const int*   dst    = (const int*)d_in[6];
    const int*   rel    = (const int*)d_in[7];
    float* out = (float*)d_out;

    char* ws = (char*)d_ws;
    size_t o = 0;
    bf16* projb = (bf16*)(ws + o);  o += 102400000ull;
    float* elr  = (float*)(ws + o); o += 25600000ull;
    short* wextT = (short*)(ws + o); o += 147456;
    int* offsets     = (int*)(ws + o); o += 400128;      // NN+1
    int* bucketCount = (int*)(ws + o); o += 1600;        // NBUCK
    int* bucketOff   = (int*)(ws + o); o += 1600;        // NBUCK+1
    int* gCursor     = (int*)(ws + o); o += 1600;
    int* pairbuf     = (int*)(ws + o); o += 6400000ull;
    int* rec_srcrel  = (int*)(ws + o); o += 6400000ull;

    hipLaunchKernelGGL(build_wextT, dim3(288), dim3(256), 0, stream, convw, attn_l, attn_r, wextT);
    hipLaunchKernelGGL(gemm_direct, dim3(NNP / 128), dim3(256), 0, stream, inputs, wextT, projb, elr);
    hipLaunchKernelGGL(zero_buckets, dim3(2), dim3(256), 0, stream, bucketCount);
    hipLaunchKernelGGL(bucket_count, dim3(NBUCK), dim3(256), 0, stream, dst, bucketCount);
    hipLaunchKernelGGL(scan_buckets, dim3(1), dim3(256), 0, stream, bucketCount, bucketOff, gCursor);
    hipLaunchKernelGGL(bucket_scatter, dim3(NBUCK), dim3(256), 0, stream, src, dst, rel, gCursor, pairbuf);
    hipLaunchKernelGGL(exact_place, dim3(NBUCK), dim3(256), 0, stream, bucketOff, pairbuf, offsets, rec_srcrel);
    hipLaunchKernelGGL(agg, dim3(25000), dim3(256), 0, stream, offsets, rec_srcrel, elr, projb, h_bias, out);
}